// Round 2
// baseline (165.253 us; speedup 1.0000x reference)
//
#include <hip/hip_runtime.h>
#include <math.h>

#define DTF 1e-3f

// ---------------------------------------------------------------------------
// Model (derived from the reference):
//   cov_t = p_t * I  (scalar Riccati chain, batch-independent, q==0, p==r exact)
//   p' = p + DT*(2*ad*p + d - (c*p+d)^2)  ==  A2*p^2 + B1*p + C0
//   s_t = c*p_t + d          (xicov = s_t * I)
//   m_t = 1 + DT*(ad - c*s_t)
//   state step:  x0' = m*x0 + kap*x1 + s*dy0 ; x1' = -kap*x0 + m*x1 + s*dy1
//     == complex z' = (m - i*kap) * z + s * (dy0 + i*dy1),  kap = DT*k
//   out_t = (c*DT) * x_t   (pre-update state)
// Chunked affine scan: phase A (per-chunk drift), B (chunk stitch), C (emit).
// ---------------------------------------------------------------------------

__global__ void setup_kernel(const float* __restrict__ cov0,
                             const float* __restrict__ coeffs,
                             float* __restrict__ mstab,   // T x float2 (m_t, s_t)
                             float* __restrict__ Qtab,    // NC x float2 (complex chunk products)
                             int T, int L, int NC)
{
    extern __shared__ float shp[];  // T floats: p_t
    const double cd  = sqrt(4.0 * 0.8 * 0.5);        // C diag
    const double dd  = 0.3 * (2.0 + 0.5) + 0.5;      // D diag = 1.25
    const double add = -0.5 * 0.3;                   // A diag = -0.15
    const float cC   = (float)cd;
    const float dcon = (float)dd;
    const float ad   = (float)add;
    const float A2   = (float)(-1e-3 * (cd * cd));
    const float B1   = (float)(1.0 + 1e-3 * (2.0 * add - 2.0 * cd * dd));
    const float C0   = (float)(1e-3 * (dd - dd * dd));
    const float kap  = DTF * coeffs[0];

    if (threadIdx.x == 0) {
        float p = cov0[0];
        for (int t = 0; t < T; ++t) {
            shp[t] = p;
            p = fmaf(A2, p * p, fmaf(B1, p, C0));
        }
    }
    __syncthreads();

    // (m_t, s_t) table
    for (int t = threadIdx.x; t < T; t += blockDim.x) {
        float pv = shp[t];
        float s  = fmaf(cC, pv, dcon);
        float m  = fmaf(DTF, fmaf(-cC, s, ad), 1.0f);
        reinterpret_cast<float2*>(mstab)[t] = make_float2(m, s);
    }

    // per-chunk complex products Q_c = prod_{t in chunk} (m_t - i*kap)
    if ((int)threadIdx.x < NC) {
        int c = threadIdx.x;
        float wr = 1.0f, wi = 0.0f;
        for (int i = 0; i < L; ++i) {
            float pv = shp[c * L + i];
            float s  = fmaf(cC, pv, dcon);
            float m  = fmaf(DTF, fmaf(-cC, s, ad), 1.0f);
            float nr = fmaf(m, wr, kap * wi);
            float ni = fmaf(m, wi, -(kap * wr));
            wr = nr; wi = ni;
        }
        reinterpret_cast<float2*>(Qtab)[c] = make_float2(wr, wi);
    }
}

__global__ __launch_bounds__(256) void phaseA_kernel(
    const float* __restrict__ dy,
    const float* __restrict__ mstab,
    float* __restrict__ Dvec,
    const float* __restrict__ coeffs,
    int T, int L, int ncShift, int total)
{
    int tid = blockIdx.x * 256 + threadIdx.x;
    if (tid >= total) return;
    const float kap = DTF * coeffs[0];
    int c  = tid & ((1 << ncShift) - 1);
    int b  = tid >> ncShift;
    int t0 = c * L;
    const float4* __restrict__ dyv =
        reinterpret_cast<const float4*>(dy + ((size_t)b * T + t0) * 2);
    const float4* __restrict__ msv =
        reinterpret_cast<const float4*>(mstab + (size_t)t0 * 2);
    float v0 = 0.0f, v1 = 0.0f;
    int n = L >> 1;
#pragma unroll 4
    for (int i = 0; i < n; ++i) {
        float4 d4 = dyv[i];
        float4 ms = msv[i];  // (m_t, s_t, m_{t+1}, s_{t+1})
        float n0 = fmaf(ms.x, v0, fmaf(kap, v1, ms.y * d4.x));
        float n1 = fmaf(ms.x, v1, fmaf(-kap, v0, ms.y * d4.y));
        float n2 = fmaf(ms.z, n0, fmaf(kap, n1, ms.w * d4.z));
        float n3 = fmaf(ms.z, n1, fmaf(-kap, n0, ms.w * d4.w));
        v0 = n2; v1 = n3;
    }
    reinterpret_cast<float2*>(Dvec)[tid] = make_float2(v0, v1);
}

__global__ void phaseB_kernel(const float* __restrict__ x0in,
                              const float* __restrict__ Qtab,
                              const float* __restrict__ Dvec,
                              float* __restrict__ Xvec,
                              int NC, int B)
{
    int b = blockIdx.x * blockDim.x + threadIdx.x;
    if (b >= B) return;
    float x = x0in[2 * b], y = x0in[2 * b + 1];
    int base = b * NC;
    for (int c = 0; c < NC; ++c) {
        reinterpret_cast<float2*>(Xvec)[base + c] = make_float2(x, y);
        float2 w = reinterpret_cast<const float2*>(Qtab)[c];
        float2 d = reinterpret_cast<const float2*>(Dvec)[base + c];
        float nx = fmaf(w.x, x, fmaf(-w.y, y, d.x));
        float ny = fmaf(w.x, y, fmaf( w.y, x, d.y));
        x = nx; y = ny;
    }
}

__global__ __launch_bounds__(256) void phaseC_kernel(
    const float* __restrict__ dy,
    const float* __restrict__ mstab,
    const float* __restrict__ Xvec,
    float* __restrict__ out,
    const float* __restrict__ coeffs,
    int T, int L, int ncShift, int total)
{
    int tid = blockIdx.x * 256 + threadIdx.x;
    if (tid >= total) return;
    const float kap = DTF * coeffs[0];
    const float cdt = (float)(sqrt(4.0 * 0.8 * 0.5) * 1e-3);  // c * DT
    int c  = tid & ((1 << ncShift) - 1);
    int b  = tid >> ncShift;
    int t0 = c * L;
    const float4* __restrict__ dyv =
        reinterpret_cast<const float4*>(dy + ((size_t)b * T + t0) * 2);
    const float4* __restrict__ msv =
        reinterpret_cast<const float4*>(mstab + (size_t)t0 * 2);
    float4* __restrict__ outv =
        reinterpret_cast<float4*>(out + ((size_t)b * T + t0) * 2);
    float2 xv = reinterpret_cast<const float2*>(Xvec)[tid];
    float v0 = xv.x, v1 = xv.y;
    int n = L >> 1;
#pragma unroll 4
    for (int i = 0; i < n; ++i) {
        float4 d4 = dyv[i];
        float4 ms = msv[i];
        float4 o;
        o.x = cdt * v0;
        o.y = cdt * v1;
        float n0 = fmaf(ms.x, v0, fmaf(kap, v1, ms.y * d4.x));
        float n1 = fmaf(ms.x, v1, fmaf(-kap, v0, ms.y * d4.y));
        o.z = cdt * n0;
        o.w = cdt * n1;
        v0 = fmaf(ms.z, n0, fmaf(kap, n1, ms.w * d4.z));
        v1 = fmaf(ms.z, n1, fmaf(-kap, n0, ms.w * d4.w));
        outv[i] = o;
    }
}

extern "C" void kernel_launch(void* const* d_in, const int* in_sizes, int n_in,
                              void* d_out, int out_size, void* d_ws, size_t ws_size,
                              hipStream_t stream)
{
    const float* dy     = (const float*)d_in[0];
    const float* x0     = (const float*)d_in[1];
    const float* cov0   = (const float*)d_in[2];
    const float* coeffs = (const float*)d_in[3];
    float* out = (float*)d_out;

    const int B = in_sizes[1] / 2;           // 8192
    const int T = in_sizes[0] / in_sizes[1]; // 2048
    const int L = 64;
    const int NC = T / L;                    // 32
    int ncShift = 0;
    while ((1 << ncShift) < NC) ++ncShift;

    // workspace layout (floats)
    float* mstab = (float*)d_ws;                 // T*2
    float* Qtab  = mstab + (size_t)T * 2;        // NC*2
    float* Dvec  = Qtab + (size_t)NC * 2;        // B*NC*2
    float* Xvec  = Dvec + (size_t)B * NC * 2;    // B*NC*2

    setup_kernel<<<1, 256, T * sizeof(float), stream>>>(cov0, coeffs, mstab, Qtab, T, L, NC);

    const int total = B * NC;
    const int blocks = (total + 255) / 256;
    phaseA_kernel<<<blocks, 256, 0, stream>>>(dy, mstab, Dvec, coeffs, T, L, ncShift, total);
    phaseB_kernel<<<(B + 255) / 256, 256, 0, stream>>>(x0, Qtab, Dvec, Xvec, NC, B);
    phaseC_kernel<<<blocks, 256, 0, stream>>>(dy, mstab, Xvec, out, coeffs, T, L, ncShift, total);
}

// Round 3
// 86.599 us; speedup vs baseline: 1.9083x; 1.9083x over previous
//
#include <hip/hip_runtime.h>
#include <math.h>

#define DTF 1e-3f

// ---------------------------------------------------------------------------
// Model (validated in round 1, absmax 7.6e-6):
//   cov_t = p_t * I  (scalar Riccati chain, batch-independent)
//   p' = A2*p^2 + B1*p + C0
//   s_t = c*p_t + d ;  m_t = 1 + DT*(ad - c*s_t)
//   state: complex z' = (m - i*kap) * z + s * (dy0 + i*dy1), kap = DT*k
//   out_t = (c*DT) * z_t   (pre-update state)
// Fused: one block per batch row; 8 steps/thread; block-wide affine scan
// (shfl_up wave scan + LDS wave aggregates). dy read once, out written once.
// ---------------------------------------------------------------------------

__device__ __forceinline__ float4 affine_combine(float4 u, float4 v) {
    // u = earlier (P,d), v = later (P,d); result = "u then v":
    // P = v.P * u.P ; d = v.P * u.d + v.d    (complex: x=Re P, y=Im P, z=Re d, w=Im d)
    float pr = fmaf(v.x, u.x, -(v.y * u.y));
    float pi = fmaf(v.x, u.y,  (v.y * u.x));
    float er = fmaf(v.x, u.z, fmaf(-v.y, u.w, v.z));
    float ei = fmaf(v.x, u.w, fmaf( v.y, u.z, v.w));
    return make_float4(pr, pi, er, ei);
}

__global__ void setup_kernel(const float* __restrict__ cov0,
                             float* __restrict__ mstab,  // T x float2 (m_t, s_t)
                             int T)
{
    extern __shared__ float shp[];  // T floats: p_t
    const double cd  = sqrt(4.0 * 0.8 * 0.5);        // C diag
    const double dd  = 0.3 * (2.0 + 0.5) + 0.5;      // D diag = 1.25
    const double add = -0.5 * 0.3;                   // A diag = -0.15
    const float cC   = (float)cd;
    const float dcon = (float)dd;
    const float ad   = (float)add;
    const float A2   = (float)(-1e-3 * (cd * cd));
    const float B1   = (float)(1.0 + 1e-3 * (2.0 * add - 2.0 * cd * dd));
    const float C0   = (float)(1e-3 * (dd - dd * dd));

    if (threadIdx.x == 0) {
        float p = cov0[0];
        for (int t = 0; t < T; ++t) {
            shp[t] = p;
            p = fmaf(fmaf(A2, p, B1), p, C0);
        }
    }
    __syncthreads();

    for (int t = threadIdx.x; t < T; t += blockDim.x) {
        float pv = shp[t];
        float s  = fmaf(cC, pv, dcon);
        float m  = fmaf(DTF, fmaf(-cC, s, ad), 1.0f);
        reinterpret_cast<float2*>(mstab)[t] = make_float2(m, s);
    }
}

__global__ __launch_bounds__(256) void fused_kernel(
    const float* __restrict__ dy,
    const float* __restrict__ x0,
    const float* __restrict__ mstab,
    const float* __restrict__ coeffs,
    float* __restrict__ out,
    int T)
{
    const int b   = blockIdx.x;
    const int tid = threadIdx.x;
    const int lane = tid & 63;
    const int wid  = tid >> 6;
    const float kap = DTF * coeffs[0];
    const float cdt = (float)(sqrt(4.0 * 0.8 * 0.5) * 1e-3);  // c * DT

    const float4* __restrict__ dyv = reinterpret_cast<const float4*>(dy + (size_t)b * T * 2);
    float4* __restrict__ outv      = reinterpret_cast<float4*>(out + (size_t)b * T * 2);
    const float4* __restrict__ msv = reinterpret_cast<const float4*>(mstab);

    // 8 timesteps per thread: 4 float4 of dy, 4 float4 of (m,s) pairs
    float4 d4[4], m4[4];
#pragma unroll
    for (int j = 0; j < 4; ++j) d4[j] = dyv[tid * 4 + j];
#pragma unroll
    for (int j = 0; j < 4; ++j) m4[j] = msv[tid * 4 + j];

    // local affine pair over 8 steps: z_out = P*z_in + d
    float Pr = 1.f, Pi = 0.f, dr = 0.f, di = 0.f;
#pragma unroll
    for (int j = 0; j < 4; ++j) {
        float m = m4[j].x, s = m4[j].y;
        float ndr = fmaf(m, dr, fmaf( kap, di, s * d4[j].x));
        float ndi = fmaf(m, di, fmaf(-kap, dr, s * d4[j].y));
        float nPr = fmaf(m, Pr,  kap * Pi);
        float nPi = fmaf(m, Pi, -(kap * Pr));
        m = m4[j].z; s = m4[j].w;
        dr = fmaf(m, ndr, fmaf( kap, ndi, s * d4[j].z));
        di = fmaf(m, ndi, fmaf(-kap, ndr, s * d4[j].w));
        Pr = fmaf(m, nPr,  kap * nPi);
        Pi = fmaf(m, nPi, -(kap * nPr));
    }

    // wave-level inclusive Hillis-Steele scan of affine pairs
    float4 v = make_float4(Pr, Pi, dr, di);
#pragma unroll
    for (int delta = 1; delta < 64; delta <<= 1) {
        float4 u;
        u.x = __shfl_up(v.x, delta);
        u.y = __shfl_up(v.y, delta);
        u.z = __shfl_up(v.z, delta);
        u.w = __shfl_up(v.w, delta);
        if (lane >= delta) v = affine_combine(u, v);
    }

    __shared__ float4 agg[4];
    if (lane == 63) agg[wid] = v;

    // exclusive in-wave prefix
    float4 ex;
    ex.x = __shfl_up(v.x, 1);
    ex.y = __shfl_up(v.y, 1);
    ex.z = __shfl_up(v.z, 1);
    ex.w = __shfl_up(v.w, 1);
    if (lane == 0) ex = make_float4(1.f, 0.f, 0.f, 0.f);

    __syncthreads();

    float4 pref = make_float4(1.f, 0.f, 0.f, 0.f);
    for (int w = 0; w < wid; ++w) pref = affine_combine(pref, agg[w]);
    float4 tot = affine_combine(pref, ex);

    // starting state for this thread's 8 steps: z = P_ex * x0 + d_ex
    float x0r = x0[2 * b], x0i = x0[2 * b + 1];
    float zr = fmaf(tot.x, x0r, fmaf(-tot.y, x0i, tot.z));
    float zi = fmaf(tot.x, x0i, fmaf( tot.y, x0r, tot.w));

    // emit: out before update
#pragma unroll
    for (int j = 0; j < 4; ++j) {
        float4 o;
        o.x = cdt * zr;
        o.y = cdt * zi;
        float m = m4[j].x, s = m4[j].y;
        float nr = fmaf(m, zr, fmaf( kap, zi, s * d4[j].x));
        float ni = fmaf(m, zi, fmaf(-kap, zr, s * d4[j].y));
        o.z = cdt * nr;
        o.w = cdt * ni;
        m = m4[j].z; s = m4[j].w;
        zr = fmaf(m, nr, fmaf( kap, ni, s * d4[j].z));
        zi = fmaf(m, ni, fmaf(-kap, nr, s * d4[j].w));
        outv[tid * 4 + j] = o;
    }
}

extern "C" void kernel_launch(void* const* d_in, const int* in_sizes, int n_in,
                              void* d_out, int out_size, void* d_ws, size_t ws_size,
                              hipStream_t stream)
{
    const float* dy     = (const float*)d_in[0];
    const float* x0     = (const float*)d_in[1];
    const float* cov0   = (const float*)d_in[2];
    const float* coeffs = (const float*)d_in[3];
    float* out = (float*)d_out;

    const int B = in_sizes[1] / 2;           // 8192
    const int T = in_sizes[0] / in_sizes[1]; // 2048

    float* mstab = (float*)d_ws;             // T*2 floats

    setup_kernel<<<1, 256, T * sizeof(float), stream>>>(cov0, mstab, T);
    fused_kernel<<<B, 256, 0, stream>>>(dy, x0, mstab, coeffs, out, T);
}

// Round 4
// 64.898 us; speedup vs baseline: 2.5463x; 1.3344x over previous
//
#include <hip/hip_runtime.h>
#include <math.h>

// ---------------------------------------------------------------------------
// Model (validated rounds 1-2, absmax 7.6e-6):
//   cov_t = p_t * I  (scalar Riccati chain, batch-independent)
//   p' = A2*p^2 + B1*p + C0 ;  s_t = c*p_t + d ;  m_t = 1 + DT*(ad - c*s_t)
//   z' = Phi_t z + s_t dyc,  Phi_t = m_t - i*kap,  kap = DT*coeffs[0]
//   out_t = (c*DT) * z_t (pre-update)
// New formulation: G_t = prod_{u<t} Phi_u  (fp64 in setup),
//   z_t = G_t * (x0 + sum_{k<t} u_k dyc_k),  u_k = s_k / G_{k+1}
//   out_t = v_t * (x0 + S_t),  v_t = cdt*G_t,  S_t = exclusive complex prefix sum
// Fused kernel: 1 block = 1 batch row. dy in / u / v / out ALL coalesced
// (u,v stored pre-permuted by setup); dy and out transposed through a
// bank-conflict-free XOR-swizzled LDS buffer. Block scan = complex add.
// ---------------------------------------------------------------------------

// swizzled phys index for logical float4 index L in a [256][4] float4 tile
__device__ __forceinline__ int swz(int L) {
    int row = L >> 2, col = L & 3;
    return (row << 2) | (col ^ ((row >> 1) & 3));
}

__global__ __launch_bounds__(256) void setup_kernel(
    const float* __restrict__ cov0,
    const float* __restrict__ coeffs,
    float* __restrict__ uperm,   // 2048 complex, permuted float4 layout
    float* __restrict__ vperm)   // 2048 complex, permuted float4 layout
{
    __shared__ float shp[2048];
    __shared__ double2 agg[4];

    const double cd  = sqrt(4.0 * 0.8 * 0.5);        // C diag
    const double dd  = 0.3 * (2.0 + 0.5) + 0.5;      // D diag
    const double add = -0.5 * 0.3;                   // A diag
    const float cC   = (float)cd;
    const float dcon = (float)dd;
    const float ad   = (float)add;
    const float A2   = (float)(-1e-3 * (cd * cd));
    const float B1   = (float)(1.0 + 1e-3 * (2.0 * add - 2.0 * cd * dd));
    const float C0   = (float)(1e-3 * (dd - dd * dd));
    const double kap = 1e-3 * (double)coeffs[0];
    const double cdt = cd * 1e-3;

    const int tid = threadIdx.x;
    const int lane = tid & 63, wid = tid >> 6;

    if (tid == 0) {
        float p = cov0[0];
        for (int t = 0; t < 2048; ++t) {
            shp[t] = p;
            p = fmaf(fmaf(A2, p, B1), p, C0);
        }
    }
    __syncthreads();

    // local product of Phi over t = 8*tid .. 8*tid+7 (fp64)
    double Pr = 1.0, Pi = 0.0;
#pragma unroll
    for (int e = 0; e < 8; ++e) {
        int t = tid * 8 + e;
        float s = fmaf(cC, shp[t], dcon);
        float m = fmaf(1e-3f, fmaf(-cC, s, ad), 1.0f);
        double nr = (double)m * Pr + kap * Pi;   // (Pr+iPi)*(m-ikap)
        double ni = (double)m * Pi - kap * Pr;
        Pr = nr; Pi = ni;
    }

    // wave inclusive scan, complex-product combine (commutative)
    double vr = Pr, vi = Pi;
#pragma unroll
    for (int delta = 1; delta < 64; delta <<= 1) {
        double ur = __shfl_up(vr, delta);
        double ui = __shfl_up(vi, delta);
        if (lane >= delta) {
            double nr = ur * vr - ui * vi;
            double ni = ur * vi + ui * vr;
            vr = nr; vi = ni;
        }
    }
    if (lane == 63) agg[wid] = make_double2(vr, vi);
    double exr = __shfl_up(vr, 1), exi = __shfl_up(vi, 1);
    if (lane == 0) { exr = 1.0; exi = 0.0; }
    __syncthreads();

    double br = 1.0, bi = 0.0;
    for (int w = 0; w < wid; ++w) {
        double2 a = agg[w];
        double nr = br * a.x - bi * a.y;
        double ni = br * a.y + bi * a.x;
        br = nr; bi = ni;
    }
    double Gr = br * exr - bi * exi;   // G at t = 8*tid
    double Gi = br * exi + bi * exr;

    float uo[16], vo[16];
#pragma unroll
    for (int e = 0; e < 8; ++e) {
        int t = tid * 8 + e;
        float s = fmaf(cC, shp[t], dcon);
        float m = fmaf(1e-3f, fmaf(-cC, s, ad), 1.0f);
        vo[2 * e]     = (float)(cdt * Gr);
        vo[2 * e + 1] = (float)(cdt * Gi);
        double nr = (double)m * Gr + kap * Gi;   // G_{t+1} = G_t * Phi_t
        double ni = (double)m * Gi - kap * Gr;
        Gr = nr; Gi = ni;
        double inv = 1.0 / (Gr * Gr + Gi * Gi);
        uo[2 * e]     = (float)( (double)s * Gr * inv);   // s*conj(G)/|G|^2
        uo[2 * e + 1] = (float)(-(double)s * Gi * inv);
    }

    // permuted store: logical float4 L = 4*tid + j  ->  position j*256 + tid
    float4* up4 = (float4*)uperm;
    float4* vp4 = (float4*)vperm;
#pragma unroll
    for (int j = 0; j < 4; ++j) {
        up4[j * 256 + tid] = make_float4(uo[4*j], uo[4*j+1], uo[4*j+2], uo[4*j+3]);
        vp4[j * 256 + tid] = make_float4(vo[4*j], vo[4*j+1], vo[4*j+2], vo[4*j+3]);
    }
}

__global__ __launch_bounds__(256) void fused_kernel(
    const float* __restrict__ dy,
    const float* __restrict__ x0,
    const float* __restrict__ uperm,
    const float* __restrict__ vperm,
    float* __restrict__ out,
    int T)
{
    __shared__ float4 buf[1024];   // 16 KiB, swizzled tile (dy, then out)
    __shared__ float2 agg[4];

    const int b   = blockIdx.x;
    const int tid = threadIdx.x;
    const int lane = tid & 63, wid = tid >> 6;

    const float4* __restrict__ dyv = reinterpret_cast<const float4*>(dy + (size_t)b * T * 2);
    const float4* __restrict__ up4 = reinterpret_cast<const float4*>(uperm);
    const float4* __restrict__ vp4 = reinterpret_cast<const float4*>(vperm);
    float4* __restrict__ outv      = reinterpret_cast<float4*>(out + (size_t)b * T * 2);

    // coalesced dy load + u load (u is permuted to match this order)
    float4 r[4], ud[4];
#pragma unroll
    for (int j = 0; j < 4; ++j) r[j]  = dyv[j * 256 + tid];
#pragma unroll
    for (int j = 0; j < 4; ++j) ud[j] = up4[j * 256 + tid];
    // ud[j] loaded at pos j*256+tid == logical float4 (4*tid'+j') ... but we
    // need OUR logical chunk: the permutation in setup was built so that
    // position j*256+tid holds logical L = 4*tid + j. So ud[j] IS u for
    // complex elements (8*tid + 2j, 8*tid + 2j + 1)?  No: it is for the
    // thread that will read it below. Stage dy to LDS; u stays in registers
    // only if ownership matches — it does NOT for r[], it DOES for ud[]? 
    // Careful: up4[j*256+tid] holds logical L=4*tid+j (per setup). This
    // thread wants exactly L=4*tid+j. MATCH. dy has no such luxury -> LDS.

#pragma unroll
    for (int j = 0; j < 4; ++j) buf[swz(j * 256 + tid)] = r[j];
    __syncthreads();

    // per-thread contiguous chunk of dy, times u -> products q
    float2 q[8];
#pragma unroll
    for (int j = 0; j < 4; ++j) {
        float4 d = buf[(tid << 2) | (j ^ ((tid >> 1) & 3))];  // logical 4*tid+j
        float4 u = ud[j];
        q[2*j].x   = fmaf(u.x, d.x, -(u.y * d.y));
        q[2*j].y   = fmaf(u.x, d.y,  (u.y * d.x));
        q[2*j+1].x = fmaf(u.z, d.z, -(u.w * d.w));
        q[2*j+1].y = fmaf(u.z, d.w,  (u.w * d.z));
    }

    // thread-local total (tree)
    float2 loc;
    {
        float ax = (q[0].x + q[1].x) + (q[2].x + q[3].x);
        float bx = (q[4].x + q[5].x) + (q[6].x + q[7].x);
        float ay = (q[0].y + q[1].y) + (q[2].y + q[3].y);
        float by = (q[4].y + q[5].y) + (q[6].y + q[7].y);
        loc = make_float2(ax + bx, ay + by);
    }

    // wave inclusive scan (complex add)
    float2 v = loc;
#pragma unroll
    for (int delta = 1; delta < 64; delta <<= 1) {
        float ux = __shfl_up(v.x, delta);
        float uy = __shfl_up(v.y, delta);
        if (lane >= delta) { v.x += ux; v.y += uy; }
    }
    if (lane == 63) agg[wid] = v;
    float2 ex;
    ex.x = __shfl_up(v.x, 1);
    ex.y = __shfl_up(v.y, 1);
    if (lane == 0) ex = make_float2(0.f, 0.f);
    __syncthreads();   // agg ready; also all buf reads complete

    float2 base = make_float2(x0[2 * b], x0[2 * b + 1]);
    for (int w = 0; w < wid; ++w) { base.x += agg[w].x; base.y += agg[w].y; }
    base.x += ex.x; base.y += ex.y;

    // emission: out_t = v_t (*) (x0 + S_t), S exclusive; v coalesced (permuted)
    float4 vt[4];
#pragma unroll
    for (int j = 0; j < 4; ++j) vt[j] = vp4[j * 256 + tid];

    float2 S = base;
#pragma unroll
    for (int j = 0; j < 4; ++j) {
        float4 o;
        float4 w = vt[j];
        o.x = fmaf(w.x, S.x, -(w.y * S.y));
        o.y = fmaf(w.x, S.y,  (w.y * S.x));
        S.x += q[2*j].x; S.y += q[2*j].y;
        o.z = fmaf(w.z, S.x, -(w.w * S.y));
        o.w = fmaf(w.z, S.y,  (w.w * S.x));
        S.x += q[2*j+1].x; S.y += q[2*j+1].y;
        buf[(tid << 2) | (j ^ ((tid >> 1) & 3))] = o;   // logical 4*tid+j
    }
    __syncthreads();

    // coalesced store
#pragma unroll
    for (int j = 0; j < 4; ++j) {
        int g = j * 256 + tid;
        outv[g] = buf[swz(g)];
    }
}

extern "C" void kernel_launch(void* const* d_in, const int* in_sizes, int n_in,
                              void* d_out, int out_size, void* d_ws, size_t ws_size,
                              hipStream_t stream)
{
    const float* dy     = (const float*)d_in[0];
    const float* x0     = (const float*)d_in[1];
    const float* cov0   = (const float*)d_in[2];
    const float* coeffs = (const float*)d_in[3];
    float* out = (float*)d_out;

    const int B = in_sizes[1] / 2;           // 8192
    const int T = in_sizes[0] / in_sizes[1]; // 2048 (kernel assumes 2048)

    float* uperm = (float*)d_ws;             // 2048 complex = 16 KiB
    float* vperm = uperm + 4096;             // 2048 complex = 16 KiB

    setup_kernel<<<1, 256, 0, stream>>>(cov0, coeffs, uperm, vperm);
    fused_kernel<<<B, 256, 0, stream>>>(dy, x0, uperm, vperm, out, T);
}

// Round 5
// 54.207 us; speedup vs baseline: 3.0486x; 1.1972x over previous
//
#include <hip/hip_runtime.h>
#include <math.h>

// ---------------------------------------------------------------------------
// Model (validated rounds 1-4, absmax 7.6e-6):
//   cov_t = p_t * I ;  p' = A2*p^2 + B1*p + C0  (batch-independent chain)
//   s_t = c*p_t + d ;  m_t = 1 + DT*(ad - c*s_t) ;  Phi_t = m_t - i*kap
//   G_t = prod_{u<t} Phi_u (fp64) ;  u_k = s_k/G_{k+1} ;  v_t = (c*DT)*G_t
//   out_t = v_t (*) (x0 + S_t),  S_t = exclusive complex prefix of u_k (*) dy_k
// Round-5 changes:
//   * setup: p-chain parallelized (32 chunks x 64 steps, 2nd-order
//     perturbation around the stable fixed point; serial depth ~100 FMA).
//   * fused: strided element ownership (L = j*256+tid) -> dy/u/v/out all
//     directly coalesced, NO LDS transpose; plain-sum prefix decomposed as
//     stripe totals + in-stripe scans; 4 rows/block (u,v kept in registers);
//     one syncthreads/row with parity-double-buffered aggregates.
// ---------------------------------------------------------------------------

__global__ __launch_bounds__(256) void setup_kernel(
    const float* __restrict__ cov0,
    const float* __restrict__ coeffs,
    float* __restrict__ utab,   // 2048 complex, linear float4 (2 steps each)
    float* __restrict__ vtab)
{
    __shared__ float php[2048];   // guessed chain p-hat
    __shared__ float phd[2048];   // d p-hat / d start
    __shared__ float phh[2048];   // 1/2! second derivative coefficient chain
    __shared__ float3 Ee[32];     // end-of-chunk (p,d,h)
    __shared__ float Del[32];     // true_start - guess per chunk
    __shared__ double2 agg[4];

    const double cdD = sqrt(4.0 * 0.8 * 0.5);     // C diag
    const double ddD = 0.3 * (2.0 + 0.5) + 0.5;   // D diag
    const double adD = -0.5 * 0.3;                // A diag
    const double aD  = -1e-3 * (cdD * cdD);
    const double bD  = 1.0 + 1e-3 * (2.0 * adD - 2.0 * cdD * ddD);
    const double cDc = 1e-3 * (ddD - ddD * ddD);

    const float cC   = (float)cdD;
    const float dcon = (float)ddD;
    const float ad   = (float)adD;
    const float A2   = (float)aD;
    const float B1   = (float)bD;
    const float C0   = (float)cDc;

    const double kap = 1e-3 * (double)coeffs[0];
    const double cdt = cdD * 1e-3;

    const int tid  = threadIdx.x;
    const int lane = tid & 63;
    const int wid  = tid >> 6;

    // stable fixed point of the map (guess for chunk starts)
    const double beta = bD - 1.0;
    const float pstar = (float)((-beta - sqrt(beta * beta - 4.0 * aD * cDc)) / (2.0 * aD));

    // --- parallel p-chain: 32 chunks x 64 steps with (p,d,h) perturbation ---
    if (tid < 32) {
        float p   = (tid == 0) ? cov0[0] : pstar;
        float dch = 1.0f, hch = 0.0f;
        const int base = tid * 64;
        for (int i = 0; i < 64; ++i) {
            php[base + i] = p;
            phd[base + i] = dch;
            phh[base + i] = hch;
            float lam = fmaf(2.0f * A2, p, B1);
            hch = fmaf(lam, hch, A2 * dch * dch);
            dch = lam * dch;
            p   = fmaf(fmaf(A2, p, B1), p, C0);
        }
        Ee[tid] = make_float3(p, dch, hch);
    }
    __syncthreads();
    if (tid == 0) {
        float D = 0.0f;
        Del[0] = 0.0f;                 // chunk 0 starts exactly at cov0
        for (int c = 0; c < 31; ++c) {
            float3 e = Ee[c];
            float tn = e.x + D * fmaf(e.z, D, e.y);   // true start of chunk c+1
            D = tn - pstar;
            Del[c + 1] = D;
        }
    }
    __syncthreads();

    // --- corrected p -> (m,s) for this thread's 8 steps, fp64 Phi product ---
    const float Dl = Del[tid >> 3];   // 8*tid .. 8*tid+7 all in chunk tid/8
    float sv[8], mv[8];
    double Pr = 1.0, Pi = 0.0;
#pragma unroll
    for (int e = 0; e < 8; ++e) {
        int t = tid * 8 + e;
        float p = php[t] + Dl * fmaf(phh[t], Dl, phd[t]);
        float s = fmaf(cC, p, dcon);
        float m = fmaf(1e-3f, fmaf(-cC, s, ad), 1.0f);
        sv[e] = s; mv[e] = m;
        double nr = (double)m * Pr + kap * Pi;   // *(m - i*kap)
        double ni = (double)m * Pi - kap * Pr;
        Pr = nr; Pi = ni;
    }

    // wave inclusive scan (complex product, fp64)
    double vr = Pr, vi = Pi;
#pragma unroll
    for (int delta = 1; delta < 64; delta <<= 1) {
        double ur = __shfl_up(vr, delta);
        double ui = __shfl_up(vi, delta);
        if (lane >= delta) {
            double nr = ur * vr - ui * vi;
            double ni = ur * vi + ui * vr;
            vr = nr; vi = ni;
        }
    }
    if (lane == 63) agg[wid] = make_double2(vr, vi);
    double exr = __shfl_up(vr, 1), exi = __shfl_up(vi, 1);
    if (lane == 0) { exr = 1.0; exi = 0.0; }
    __syncthreads();

    double br = 1.0, bi = 0.0;
    for (int w = 0; w < wid; ++w) {
        double2 a = agg[w];
        double nr = br * a.x - bi * a.y;
        double ni = br * a.y + bi * a.x;
        br = nr; bi = ni;
    }
    double Gr = br * exr - bi * exi;   // G at t = 8*tid
    double Gi = br * exi + bi * exr;

    float uo[16], vo[16];
#pragma unroll
    for (int e = 0; e < 8; ++e) {
        vo[2 * e]     = (float)(cdt * Gr);
        vo[2 * e + 1] = (float)(cdt * Gi);
        double nr = (double)mv[e] * Gr + kap * Gi;   // G_{t+1}
        double ni = (double)mv[e] * Gi - kap * Gr;
        Gr = nr; Gi = ni;
        double inv = 1.0 / (Gr * Gr + Gi * Gi);
        uo[2 * e]     = (float)( (double)sv[e] * Gr * inv);  // s*conj(G)/|G|^2
        uo[2 * e + 1] = (float)(-(double)sv[e] * Gi * inv);
    }

    float4* up4 = (float4*)utab;
    float4* vp4 = (float4*)vtab;
#pragma unroll
    for (int j = 0; j < 4; ++j) {
        up4[4 * tid + j] = make_float4(uo[4*j], uo[4*j+1], uo[4*j+2], uo[4*j+3]);
        vp4[4 * tid + j] = make_float4(vo[4*j], vo[4*j+1], vo[4*j+2], vo[4*j+3]);
    }
}

__global__ __launch_bounds__(256) void fused_kernel(
    const float* __restrict__ dy,
    const float* __restrict__ x0,
    const float* __restrict__ utab,
    const float* __restrict__ vtab,
    float* __restrict__ out,
    int T)
{
    __shared__ float2 aggs[2][4][4];   // [row parity][stripe][wave]

    const int tid  = threadIdx.x;
    const int lane = tid & 63;
    const int wid  = tid >> 6;
    const int R    = 4;
    const int b0   = blockIdx.x * R;

    const float4* __restrict__ up4 = reinterpret_cast<const float4*>(utab);
    const float4* __restrict__ vp4 = reinterpret_cast<const float4*>(vtab);
    float4 ud[4], vt[4];
#pragma unroll
    for (int j = 0; j < 4; ++j) ud[j] = up4[j * 256 + tid];
#pragma unroll
    for (int j = 0; j < 4; ++j) vt[j] = vp4[j * 256 + tid];

    const float4* __restrict__ dyv =
        reinterpret_cast<const float4*>(dy + (size_t)b0 * T * 2);
    float4* __restrict__ outv =
        reinterpret_cast<float4*>(out + (size_t)b0 * T * 2);
    const int row4 = T >> 1;   // float4 per row

    float4 d4[4];
#pragma unroll
    for (int j = 0; j < 4; ++j) d4[j] = dyv[j * 256 + tid];

    for (int r = 0; r < R; ++r) {
        // products q_k = u_k (*) dy_k ; per-stripe pair sums
        float2 q[8], qq[4];
#pragma unroll
        for (int j = 0; j < 4; ++j) {
            float4 u = ud[j], d = d4[j];
            q[2*j].x   = fmaf(u.x, d.x, -(u.y * d.y));
            q[2*j].y   = fmaf(u.x, d.y,  (u.y * d.x));
            q[2*j+1].x = fmaf(u.z, d.z, -(u.w * d.w));
            q[2*j+1].y = fmaf(u.z, d.w,  (u.w * d.z));
            qq[j].x = q[2*j].x + q[2*j+1].x;
            qq[j].y = q[2*j].y + q[2*j+1].y;
        }
        // prefetch next row's dy (d4 dead after q)
        if (r + 1 < R) {
#pragma unroll
            for (int j = 0; j < 4; ++j)
                d4[j] = dyv[(r + 1) * row4 + j * 256 + tid];
        }
        // 4 wave-level inclusive scans (complex add)
        float2 incl[4];
#pragma unroll
        for (int j = 0; j < 4; ++j) incl[j] = qq[j];
#pragma unroll
        for (int delta = 1; delta < 64; delta <<= 1) {
#pragma unroll
            for (int j = 0; j < 4; ++j) {
                float ux = __shfl_up(incl[j].x, delta);
                float uy = __shfl_up(incl[j].y, delta);
                if (lane >= delta) { incl[j].x += ux; incl[j].y += uy; }
            }
        }
        const int par = r & 1;
        if (lane == 63) {
#pragma unroll
            for (int j = 0; j < 4; ++j) aggs[par][j][wid] = incl[j];
        }
        float2 ex[4];
#pragma unroll
        for (int j = 0; j < 4; ++j) {
            ex[j].x = __shfl_up(incl[j].x, 1);
            ex[j].y = __shfl_up(incl[j].y, 1);
            if (lane == 0) ex[j] = make_float2(0.f, 0.f);
        }
        __syncthreads();

        const int b = b0 + r;
        float2 run = make_float2(x0[2 * b], x0[2 * b + 1]);
        float2 Sst[4];
#pragma unroll
        for (int j = 0; j < 4; ++j) {
            float2 wp  = make_float2(0.f, 0.f);
            float2 tot = make_float2(0.f, 0.f);
#pragma unroll
            for (int w = 0; w < 4; ++w) {
                float2 a = aggs[par][j][w];
                tot.x += a.x; tot.y += a.y;
                if (w < wid) { wp.x += a.x; wp.y += a.y; }
            }
            Sst[j].x = run.x + wp.x + ex[j].x;
            Sst[j].y = run.y + wp.y + ex[j].y;
            run.x += tot.x; run.y += tot.y;
        }
        // emission: stripe j covers timesteps 2L, 2L+1 at L = j*256 + tid
#pragma unroll
        for (int j = 0; j < 4; ++j) {
            float2 S = Sst[j];
            float4 w = vt[j], o;
            o.x = fmaf(w.x, S.x, -(w.y * S.y));
            o.y = fmaf(w.x, S.y,  (w.y * S.x));
            S.x += q[2*j].x; S.y += q[2*j].y;
            o.z = fmaf(w.z, S.x, -(w.w * S.y));
            o.w = fmaf(w.z, S.y,  (w.w * S.x));
            outv[r * row4 + j * 256 + tid] = o;
        }
    }
}

extern "C" void kernel_launch(void* const* d_in, const int* in_sizes, int n_in,
                              void* d_out, int out_size, void* d_ws, size_t ws_size,
                              hipStream_t stream)
{
    const float* dy     = (const float*)d_in[0];
    const float* x0     = (const float*)d_in[1];
    const float* cov0   = (const float*)d_in[2];
    const float* coeffs = (const float*)d_in[3];
    float* out = (float*)d_out;

    const int B = in_sizes[1] / 2;           // 8192
    const int T = in_sizes[0] / in_sizes[1]; // 2048 (setup assumes 2048)

    float* utab = (float*)d_ws;              // 2048 complex = 16 KiB
    float* vtab = utab + 4096;               // 2048 complex = 16 KiB

    setup_kernel<<<1, 256, 0, stream>>>(cov0, coeffs, utab, vtab);
    fused_kernel<<<B / 4, 256, 0, stream>>>(dy, x0, utab, vtab, out, T);
}

// Round 7
// 50.999 us; speedup vs baseline: 3.2403x; 1.0629x over previous
//
#include <hip/hip_runtime.h>
#include <math.h>

// ---------------------------------------------------------------------------
// Model (validated rounds 1-5, absmax 7.6e-6):
//   cov_t = p_t * I ;  p' = A2*p^2 + B1*p + C0  (batch-independent chain)
//   s_t = c*p_t + d ;  m_t = 1 + DT*(ad - c*s_t) ;  Phi_t = m_t - i*kap
//   G_t = prod_{u<t} Phi_u (fp64) ;  u_k = s_k/G_{k+1} ;  v_t = (c*DT)*G_t
//   out_t = v_t (*) (x0 + S_t),  S_t = exclusive complex prefix of u_k (*) dy_k
// Round-6 changes (round-5 retry, compile fix):
//   * wave scan: shfl_up (ds_bpermute, LDS pipe) replaced by DPP VALU-only
//     scan (row_shr 1/2/4/8 + row_bcast 15/31, identity-0).
//   * exclusive prefix = inclusive - own (1 ulp, budget 2.5e-5).
//   * non-temporal out stores via native ext_vector float4 (HIP float4 class
//     is rejected by __builtin_nontemporal_store).
// ---------------------------------------------------------------------------

typedef float nfloat4 __attribute__((ext_vector_type(4)));

template <int CTRL, int ROW_MASK>
__device__ __forceinline__ float dpp0(float x) {
    return __int_as_float(__builtin_amdgcn_update_dpp(
        0, __float_as_int(x), CTRL, ROW_MASK, 0xf, false));
}

// wave64 inclusive add-scan, VALU-only (LLVM AtomicOptimizer idiom)
__device__ __forceinline__ float wave_scan_add(float x) {
    x += dpp0<0x111, 0xf>(x);   // row_shr:1
    x += dpp0<0x112, 0xf>(x);   // row_shr:2
    x += dpp0<0x114, 0xf>(x);   // row_shr:4
    x += dpp0<0x118, 0xf>(x);   // row_shr:8
    x += dpp0<0x142, 0xa>(x);   // row_bcast:15 -> rows 1,3
    x += dpp0<0x143, 0xc>(x);   // row_bcast:31 -> rows 2,3
    return x;
}

__global__ __launch_bounds__(256) void setup_kernel(
    const float* __restrict__ cov0,
    const float* __restrict__ coeffs,
    float* __restrict__ utab,   // 2048 complex, linear float4 (2 steps each)
    float* __restrict__ vtab)
{
    __shared__ float php[2048];   // guessed chain p-hat
    __shared__ float phd[2048];   // d p-hat / d start
    __shared__ float phh[2048];   // second-order coefficient chain
    __shared__ float3 Ee[32];     // end-of-chunk (p,d,h)
    __shared__ float Del[32];     // true_start - guess per chunk
    __shared__ double2 agg[4];

    const double cdD = sqrt(4.0 * 0.8 * 0.5);     // C diag
    const double ddD = 0.3 * (2.0 + 0.5) + 0.5;   // D diag
    const double adD = -0.5 * 0.3;                // A diag
    const double aD  = -1e-3 * (cdD * cdD);
    const double bD  = 1.0 + 1e-3 * (2.0 * adD - 2.0 * cdD * ddD);
    const double cDc = 1e-3 * (ddD - ddD * ddD);

    const float cC   = (float)cdD;
    const float dcon = (float)ddD;
    const float ad   = (float)adD;
    const float A2   = (float)aD;
    const float B1   = (float)bD;
    const float C0   = (float)cDc;

    const double kap = 1e-3 * (double)coeffs[0];
    const double cdt = cdD * 1e-3;

    const int tid  = threadIdx.x;
    const int lane = tid & 63;
    const int wid  = tid >> 6;

    const double beta = bD - 1.0;
    const float pstar = (float)((-beta - sqrt(beta * beta - 4.0 * aD * cDc)) / (2.0 * aD));

    // --- parallel p-chain: 32 chunks x 64 steps, 2nd-order perturbation ---
    if (tid < 32) {
        float p   = (tid == 0) ? cov0[0] : pstar;
        float dch = 1.0f, hch = 0.0f;
        const int base = tid * 64;
        for (int i = 0; i < 64; ++i) {
            php[base + i] = p;
            phd[base + i] = dch;
            phh[base + i] = hch;
            float lam = fmaf(2.0f * A2, p, B1);
            hch = fmaf(lam, hch, A2 * dch * dch);
            dch = lam * dch;
            p   = fmaf(fmaf(A2, p, B1), p, C0);
        }
        Ee[tid] = make_float3(p, dch, hch);
    }
    __syncthreads();
    if (tid == 0) {
        float D = 0.0f;
        Del[0] = 0.0f;
        for (int c = 0; c < 31; ++c) {
            float3 e = Ee[c];
            float tn = e.x + D * fmaf(e.z, D, e.y);
            D = tn - pstar;
            Del[c + 1] = D;
        }
    }
    __syncthreads();

    // --- corrected p -> (m,s), fp64 Phi product over this thread's 8 steps ---
    const float Dl = Del[tid >> 3];
    float sv[8], mv[8];
    double Pr = 1.0, Pi = 0.0;
#pragma unroll
    for (int e = 0; e < 8; ++e) {
        int t = tid * 8 + e;
        float p = php[t] + Dl * fmaf(phh[t], Dl, phd[t]);
        float s = fmaf(cC, p, dcon);
        float m = fmaf(1e-3f, fmaf(-cC, s, ad), 1.0f);
        sv[e] = s; mv[e] = m;
        double nr = (double)m * Pr + kap * Pi;
        double ni = (double)m * Pi - kap * Pr;
        Pr = nr; Pi = ni;
    }

    // wave inclusive scan (complex product, fp64) — setup only, keep shfl
    double vr = Pr, vi = Pi;
#pragma unroll
    for (int delta = 1; delta < 64; delta <<= 1) {
        double ur = __shfl_up(vr, delta);
        double ui = __shfl_up(vi, delta);
        if (lane >= delta) {
            double nr = ur * vr - ui * vi;
            double ni = ur * vi + ui * vr;
            vr = nr; vi = ni;
        }
    }
    if (lane == 63) agg[wid] = make_double2(vr, vi);
    double exr = __shfl_up(vr, 1), exi = __shfl_up(vi, 1);
    if (lane == 0) { exr = 1.0; exi = 0.0; }
    __syncthreads();

    double br = 1.0, bi = 0.0;
    for (int w = 0; w < wid; ++w) {
        double2 a = agg[w];
        double nr = br * a.x - bi * a.y;
        double ni = br * a.y + bi * a.x;
        br = nr; bi = ni;
    }
    double Gr = br * exr - bi * exi;
    double Gi = br * exi + bi * exr;

    float uo[16], vo[16];
#pragma unroll
    for (int e = 0; e < 8; ++e) {
        vo[2 * e]     = (float)(cdt * Gr);
        vo[2 * e + 1] = (float)(cdt * Gi);
        double nr = (double)mv[e] * Gr + kap * Gi;
        double ni = (double)mv[e] * Gi - kap * Gr;
        Gr = nr; Gi = ni;
        double inv = 1.0 / (Gr * Gr + Gi * Gi);
        uo[2 * e]     = (float)( (double)sv[e] * Gr * inv);
        uo[2 * e + 1] = (float)(-(double)sv[e] * Gi * inv);
    }

    float4* up4 = (float4*)utab;
    float4* vp4 = (float4*)vtab;
#pragma unroll
    for (int j = 0; j < 4; ++j) {
        up4[4 * tid + j] = make_float4(uo[4*j], uo[4*j+1], uo[4*j+2], uo[4*j+3]);
        vp4[4 * tid + j] = make_float4(vo[4*j], vo[4*j+1], vo[4*j+2], vo[4*j+3]);
    }
}

__global__ __launch_bounds__(256) void fused_kernel(
    const float* __restrict__ dy,
    const float* __restrict__ x0,
    const float* __restrict__ utab,
    const float* __restrict__ vtab,
    float* __restrict__ out,
    int T)
{
    __shared__ float2 aggs[2][4][4];   // [row parity][stripe][wave]

    const int tid  = threadIdx.x;
    const int lane = tid & 63;
    const int wid  = tid >> 6;
    const int R    = 4;
    const int b0   = blockIdx.x * R;

    const float4* __restrict__ up4 = reinterpret_cast<const float4*>(utab);
    const float4* __restrict__ vp4 = reinterpret_cast<const float4*>(vtab);
    float4 ud[4], vt[4];
#pragma unroll
    for (int j = 0; j < 4; ++j) ud[j] = up4[j * 256 + tid];
#pragma unroll
    for (int j = 0; j < 4; ++j) vt[j] = vp4[j * 256 + tid];

    const float4* __restrict__ dyv =
        reinterpret_cast<const float4*>(dy + (size_t)b0 * T * 2);
    nfloat4* __restrict__ outv =
        reinterpret_cast<nfloat4*>(out + (size_t)b0 * T * 2);
    const int row4 = T >> 1;   // float4 per row

    float4 d4[4];
#pragma unroll
    for (int j = 0; j < 4; ++j) d4[j] = dyv[j * 256 + tid];

    for (int r = 0; r < R; ++r) {
        // products q_k = u_k (*) dy_k ; per-stripe pair sums
        float2 q[8], qq[4];
#pragma unroll
        for (int j = 0; j < 4; ++j) {
            float4 u = ud[j], d = d4[j];
            q[2*j].x   = fmaf(u.x, d.x, -(u.y * d.y));
            q[2*j].y   = fmaf(u.x, d.y,  (u.y * d.x));
            q[2*j+1].x = fmaf(u.z, d.z, -(u.w * d.w));
            q[2*j+1].y = fmaf(u.z, d.w,  (u.w * d.z));
            qq[j].x = q[2*j].x + q[2*j+1].x;
            qq[j].y = q[2*j].y + q[2*j+1].y;
        }
        // prefetch next row's dy (d4 dead after q)
        if (r + 1 < R) {
#pragma unroll
            for (int j = 0; j < 4; ++j)
                d4[j] = dyv[(r + 1) * row4 + j * 256 + tid];
        }
        // 4 wave-level inclusive scans (complex add) — DPP, VALU-only
        float2 incl[4];
#pragma unroll
        for (int j = 0; j < 4; ++j) {
            incl[j].x = wave_scan_add(qq[j].x);
            incl[j].y = wave_scan_add(qq[j].y);
        }
        const int par = r & 1;
        if (lane == 63) {
#pragma unroll
            for (int j = 0; j < 4; ++j) aggs[par][j][wid] = incl[j];
        }
        __syncthreads();

        const int b = b0 + r;
        float2 run = make_float2(x0[2 * b], x0[2 * b + 1]);
        float2 Sst[4];
#pragma unroll
        for (int j = 0; j < 4; ++j) {
            float2 wp  = make_float2(0.f, 0.f);
            float2 tot = make_float2(0.f, 0.f);
#pragma unroll
            for (int w = 0; w < 4; ++w) {
                float2 a = aggs[par][j][w];
                tot.x += a.x; tot.y += a.y;
                if (w < wid) { wp.x += a.x; wp.y += a.y; }
            }
            // exclusive in-wave prefix = inclusive - own stripe sum (1 ulp)
            Sst[j].x = run.x + wp.x + (incl[j].x - qq[j].x);
            Sst[j].y = run.y + wp.y + (incl[j].y - qq[j].y);
            run.x += tot.x; run.y += tot.y;
        }
        // emission: stripe j covers timesteps 2L, 2L+1 at L = j*256 + tid
#pragma unroll
        for (int j = 0; j < 4; ++j) {
            float2 S = Sst[j];
            float4 w = vt[j];
            nfloat4 o;
            o.x = fmaf(w.x, S.x, -(w.y * S.y));
            o.y = fmaf(w.x, S.y,  (w.y * S.x));
            S.x += q[2*j].x; S.y += q[2*j].y;
            o.z = fmaf(w.z, S.x, -(w.w * S.y));
            o.w = fmaf(w.z, S.y,  (w.w * S.x));
            __builtin_nontemporal_store(o, &outv[r * row4 + j * 256 + tid]);
        }
    }
}

extern "C" void kernel_launch(void* const* d_in, const int* in_sizes, int n_in,
                              void* d_out, int out_size, void* d_ws, size_t ws_size,
                              hipStream_t stream)
{
    const float* dy     = (const float*)d_in[0];
    const float* x0     = (const float*)d_in[1];
    const float* cov0   = (const float*)d_in[2];
    const float* coeffs = (const float*)d_in[3];
    float* out = (float*)d_out;

    const int B = in_sizes[1] / 2;           // 8192
    const int T = in_sizes[0] / in_sizes[1]; // 2048 (setup assumes 2048)

    float* utab = (float*)d_ws;              // 2048 complex = 16 KiB
    float* vtab = utab + 4096;               // 2048 complex = 16 KiB

    setup_kernel<<<1, 256, 0, stream>>>(cov0, coeffs, utab, vtab);
    fused_kernel<<<B / 4, 256, 0, stream>>>(dy, x0, utab, vtab, out, T);
}

// Round 8
// 49.042 us; speedup vs baseline: 3.3696x; 1.0399x over previous
//
#include <hip/hip_runtime.h>
#include <math.h>

// ---------------------------------------------------------------------------
// Model (validated rounds 1-7, absmax 7.6e-6):
//   cov_t = p_t * I ;  p' = A2*p^2 + B1*p + C0  (batch-independent chain)
//   s_t = c*p_t + d ;  m_t = 1 + DT*(ad - c*s_t) ;  Phi_t = m_t - i*kap
//   G_t = prod_{u<t} Phi_u (fp64) ;  u_k = s_k/G_{k+1} ;  v_t = (c*DT)*G_t
//   out_t = v_t (*) (x0 + S_t),  S_t = exclusive complex prefix of u_k (*) dy_k
// Round-8 changes (occupancy, not scan, is the bottleneck — R7 counters:
// VALUBusy 20%, Occupancy 25%, HBM 2.5TB/s, VGPR 76 = 4-waves/SIMD bin):
//   * R=1: one row per 256-thread block, grid 8192 (was 4 rows/block).
//     u/v are L2-resident; re-reading them per block is nearly free.
//   * v loaded only at emission; u folded into q immediately; no prefetch
//     registers; single agg buffer, one barrier per block.
//   * __launch_bounds__(256, 8) to force VGPR<=64 -> 8 waves/SIMD.
// ---------------------------------------------------------------------------

typedef float nfloat4 __attribute__((ext_vector_type(4)));

template <int CTRL, int ROW_MASK>
__device__ __forceinline__ float dpp0(float x) {
    return __int_as_float(__builtin_amdgcn_update_dpp(
        0, __float_as_int(x), CTRL, ROW_MASK, 0xf, false));
}

// wave64 inclusive add-scan, VALU-only (LLVM AtomicOptimizer idiom)
__device__ __forceinline__ float wave_scan_add(float x) {
    x += dpp0<0x111, 0xf>(x);   // row_shr:1
    x += dpp0<0x112, 0xf>(x);   // row_shr:2
    x += dpp0<0x114, 0xf>(x);   // row_shr:4
    x += dpp0<0x118, 0xf>(x);   // row_shr:8
    x += dpp0<0x142, 0xa>(x);   // row_bcast:15 -> rows 1,3
    x += dpp0<0x143, 0xc>(x);   // row_bcast:31 -> rows 2,3
    return x;
}

__global__ __launch_bounds__(256) void setup_kernel(
    const float* __restrict__ cov0,
    const float* __restrict__ coeffs,
    float* __restrict__ utab,   // 2048 complex, linear float4 (2 steps each)
    float* __restrict__ vtab)
{
    __shared__ float php[2048];   // guessed chain p-hat
    __shared__ float phd[2048];   // d p-hat / d start
    __shared__ float phh[2048];   // second-order coefficient chain
    __shared__ float3 Ee[32];     // end-of-chunk (p,d,h)
    __shared__ float Del[32];     // true_start - guess per chunk
    __shared__ double2 agg[4];

    const double cdD = sqrt(4.0 * 0.8 * 0.5);     // C diag
    const double ddD = 0.3 * (2.0 + 0.5) + 0.5;   // D diag
    const double adD = -0.5 * 0.3;                // A diag
    const double aD  = -1e-3 * (cdD * cdD);
    const double bD  = 1.0 + 1e-3 * (2.0 * adD - 2.0 * cdD * ddD);
    const double cDc = 1e-3 * (ddD - ddD * ddD);

    const float cC   = (float)cdD;
    const float dcon = (float)ddD;
    const float ad   = (float)adD;
    const float A2   = (float)aD;
    const float B1   = (float)bD;
    const float C0   = (float)cDc;

    const double kap = 1e-3 * (double)coeffs[0];
    const double cdt = cdD * 1e-3;

    const int tid  = threadIdx.x;
    const int lane = tid & 63;
    const int wid  = tid >> 6;

    const double beta = bD - 1.0;
    const float pstar = (float)((-beta - sqrt(beta * beta - 4.0 * aD * cDc)) / (2.0 * aD));

    // --- parallel p-chain: 32 chunks x 64 steps, 2nd-order perturbation ---
    if (tid < 32) {
        float p   = (tid == 0) ? cov0[0] : pstar;
        float dch = 1.0f, hch = 0.0f;
        const int base = tid * 64;
        for (int i = 0; i < 64; ++i) {
            php[base + i] = p;
            phd[base + i] = dch;
            phh[base + i] = hch;
            float lam = fmaf(2.0f * A2, p, B1);
            hch = fmaf(lam, hch, A2 * dch * dch);
            dch = lam * dch;
            p   = fmaf(fmaf(A2, p, B1), p, C0);
        }
        Ee[tid] = make_float3(p, dch, hch);
    }
    __syncthreads();
    if (tid == 0) {
        float D = 0.0f;
        Del[0] = 0.0f;
        for (int c = 0; c < 31; ++c) {
            float3 e = Ee[c];
            float tn = e.x + D * fmaf(e.z, D, e.y);
            D = tn - pstar;
            Del[c + 1] = D;
        }
    }
    __syncthreads();

    // --- corrected p -> (m,s), fp64 Phi product over this thread's 8 steps ---
    const float Dl = Del[tid >> 3];
    float sv[8], mv[8];
    double Pr = 1.0, Pi = 0.0;
#pragma unroll
    for (int e = 0; e < 8; ++e) {
        int t = tid * 8 + e;
        float p = php[t] + Dl * fmaf(phh[t], Dl, phd[t]);
        float s = fmaf(cC, p, dcon);
        float m = fmaf(1e-3f, fmaf(-cC, s, ad), 1.0f);
        sv[e] = s; mv[e] = m;
        double nr = (double)m * Pr + kap * Pi;
        double ni = (double)m * Pi - kap * Pr;
        Pr = nr; Pi = ni;
    }

    // wave inclusive scan (complex product, fp64) — setup only, keep shfl
    double vr = Pr, vi = Pi;
#pragma unroll
    for (int delta = 1; delta < 64; delta <<= 1) {
        double ur = __shfl_up(vr, delta);
        double ui = __shfl_up(vi, delta);
        if (lane >= delta) {
            double nr = ur * vr - ui * vi;
            double ni = ur * vi + ui * vr;
            vr = nr; vi = ni;
        }
    }
    if (lane == 63) agg[wid] = make_double2(vr, vi);
    double exr = __shfl_up(vr, 1), exi = __shfl_up(vi, 1);
    if (lane == 0) { exr = 1.0; exi = 0.0; }
    __syncthreads();

    double br = 1.0, bi = 0.0;
    for (int w = 0; w < wid; ++w) {
        double2 a = agg[w];
        double nr = br * a.x - bi * a.y;
        double ni = br * a.y + bi * a.x;
        br = nr; bi = ni;
    }
    double Gr = br * exr - bi * exi;
    double Gi = br * exi + bi * exr;

    float uo[16], vo[16];
#pragma unroll
    for (int e = 0; e < 8; ++e) {
        vo[2 * e]     = (float)(cdt * Gr);
        vo[2 * e + 1] = (float)(cdt * Gi);
        double nr = (double)mv[e] * Gr + kap * Gi;
        double ni = (double)mv[e] * Gi - kap * Gr;
        Gr = nr; Gi = ni;
        double inv = 1.0 / (Gr * Gr + Gi * Gi);
        uo[2 * e]     = (float)( (double)sv[e] * Gr * inv);
        uo[2 * e + 1] = (float)(-(double)sv[e] * Gi * inv);
    }

    float4* up4 = (float4*)utab;
    float4* vp4 = (float4*)vtab;
#pragma unroll
    for (int j = 0; j < 4; ++j) {
        up4[4 * tid + j] = make_float4(uo[4*j], uo[4*j+1], uo[4*j+2], uo[4*j+3]);
        vp4[4 * tid + j] = make_float4(vo[4*j], vo[4*j+1], vo[4*j+2], vo[4*j+3]);
    }
}

__global__ __launch_bounds__(256, 8) void fused_kernel(
    const float* __restrict__ dy,
    const float* __restrict__ x0,
    const float* __restrict__ utab,
    const float* __restrict__ vtab,
    float* __restrict__ out,
    int T)
{
    __shared__ float2 aggs[4][4];   // [stripe][wave]

    const int tid  = threadIdx.x;
    const int lane = tid & 63;
    const int wid  = tid >> 6;
    const int b    = blockIdx.x;

    const float4* __restrict__ up4 = reinterpret_cast<const float4*>(utab);
    const float4* __restrict__ vp4 = reinterpret_cast<const float4*>(vtab);
    const float4* __restrict__ dyv =
        reinterpret_cast<const float4*>(dy + (size_t)b * T * 2);
    nfloat4* __restrict__ outv =
        reinterpret_cast<nfloat4*>(out + (size_t)b * T * 2);

    // load dy + u, fold immediately into products q ; per-stripe pair sums
    float2 q[8], qq[4];
#pragma unroll
    for (int j = 0; j < 4; ++j) {
        float4 d = dyv[j * 256 + tid];
        float4 u = up4[j * 256 + tid];
        q[2*j].x   = fmaf(u.x, d.x, -(u.y * d.y));
        q[2*j].y   = fmaf(u.x, d.y,  (u.y * d.x));
        q[2*j+1].x = fmaf(u.z, d.z, -(u.w * d.w));
        q[2*j+1].y = fmaf(u.z, d.w,  (u.w * d.z));
        qq[j].x = q[2*j].x + q[2*j+1].x;
        qq[j].y = q[2*j].y + q[2*j+1].y;
    }

    // 4 wave-level inclusive scans (complex add) — DPP, VALU-only
    float2 incl[4];
#pragma unroll
    for (int j = 0; j < 4; ++j) {
        incl[j].x = wave_scan_add(qq[j].x);
        incl[j].y = wave_scan_add(qq[j].y);
    }
    if (lane == 63) {
#pragma unroll
        for (int j = 0; j < 4; ++j) aggs[j][wid] = incl[j];
    }
    __syncthreads();

    float2 run = make_float2(x0[2 * b], x0[2 * b + 1]);
    float2 Sst[4];
#pragma unroll
    for (int j = 0; j < 4; ++j) {
        float2 wp  = make_float2(0.f, 0.f);
        float2 tot = make_float2(0.f, 0.f);
#pragma unroll
        for (int w = 0; w < 4; ++w) {
            float2 a = aggs[j][w];
            tot.x += a.x; tot.y += a.y;
            if (w < wid) { wp.x += a.x; wp.y += a.y; }
        }
        // exclusive in-wave prefix = inclusive - own stripe sum (1 ulp)
        Sst[j].x = run.x + wp.x + (incl[j].x - qq[j].x);
        Sst[j].y = run.y + wp.y + (incl[j].y - qq[j].y);
        run.x += tot.x; run.y += tot.y;
    }

    // emission: stripe j covers timesteps 2L, 2L+1 at L = j*256 + tid
#pragma unroll
    for (int j = 0; j < 4; ++j) {
        float4 w = vp4[j * 256 + tid];
        float2 S = Sst[j];
        nfloat4 o;
        o.x = fmaf(w.x, S.x, -(w.y * S.y));
        o.y = fmaf(w.x, S.y,  (w.y * S.x));
        S.x += q[2*j].x; S.y += q[2*j].y;
        o.z = fmaf(w.z, S.x, -(w.w * S.y));
        o.w = fmaf(w.z, S.y,  (w.w * S.x));
        __builtin_nontemporal_store(o, &outv[j * 256 + tid]);
    }
}

extern "C" void kernel_launch(void* const* d_in, const int* in_sizes, int n_in,
                              void* d_out, int out_size, void* d_ws, size_t ws_size,
                              hipStream_t stream)
{
    const float* dy     = (const float*)d_in[0];
    const float* x0     = (const float*)d_in[1];
    const float* cov0   = (const float*)d_in[2];
    const float* coeffs = (const float*)d_in[3];
    float* out = (float*)d_out;

    const int B = in_sizes[1] / 2;           // 8192
    const int T = in_sizes[0] / in_sizes[1]; // 2048 (setup assumes 2048)

    float* utab = (float*)d_ws;              // 2048 complex = 16 KiB
    float* vtab = utab + 4096;               // 2048 complex = 16 KiB

    setup_kernel<<<1, 256, 0, stream>>>(cov0, coeffs, utab, vtab);
    fused_kernel<<<B, 256, 0, stream>>>(dy, x0, utab, vtab, out, T);
}